// Round 4
// baseline (96.934 us; speedup 1.0000x reference)
//
#include <hip/hip_runtime.h>
#include <math.h>

// Problem constants (ConvAttention: B=8, C=192, H=W=28, heads=6, ch=32, G=4)
namespace {
constexpr int kB = 8;
constexpr int kC = 192;
constexpr int kH = 28;
constexpr int kW = 28;
constexpr int kN = 784;          // kH * kW
constexpr int kHEADS = 6;
constexpr int kG = 4;
constexpr float kEPS = 1e-5f;
constexpr float kSCALE = 0.07216878364870322f;  // 192^-0.5
constexpr int kNP = 800;         // padded key rows (25 tiles of 32)
constexpr int kXP = 832;         // padded n rows for AO (13 tiles of 64)
}

typedef __attribute__((ext_vector_type(8))) short bf16x8;
typedef __attribute__((ext_vector_type(4))) float f32x4;

// f32 -> bf16 bits, round-to-nearest-even
static __device__ __forceinline__ unsigned short f2bf(float f) {
    union { float f; unsigned int u; } v; v.f = f;
    unsigned int r = v.u + 0x7fffu + ((v.u >> 16) & 1u);
    return (unsigned short)(r >> 16);
}

// ---------------------------------------------------------------------------
// K0: weight prep + K/V pad-row zeroing.
// Wq/Wk/Wv: f32->bf16. Wo: bf16 with column permutation
// Wo'[o][h*32+c] = po_w[o][c*6+h]. Also zeroes Kb/Vb key rows [784,800)
// so attention never consumes uninitialized pad memory.
// ---------------------------------------------------------------------------
__global__ __launch_bounds__(256) void prep_kernel(
    const float* __restrict__ pqw, const float* __restrict__ pkw,
    const float* __restrict__ pvw, const float* __restrict__ pow_,
    unsigned short* __restrict__ Wq, unsigned short* __restrict__ Wk,
    unsigned short* __restrict__ Wv, unsigned short* __restrict__ Wo,
    unsigned short* __restrict__ Kb, unsigned short* __restrict__ Vb)
{
    const int idx = blockIdx.x * 256 + threadIdx.x;
    const int WTOT = 4 * kC * kC;  // 147456
    if (idx < WTOT) {
        const int mat = idx / (kC * kC);
        const int r = idx % (kC * kC);
        if (mat == 0)      Wq[r] = f2bf(pqw[r]);
        else if (mat == 1) Wk[r] = f2bf(pkw[r]);
        else if (mat == 2) Wv[r] = f2bf(pvw[r]);
        else {
            const int o = r / kC, c = r % kC;
            const int h = c >> 5, ch = c & 31;
            Wo[o * kC + c] = f2bf(pow_[o * kC + ch * kHEADS + h]);
        }
    } else {
        int r = idx - WTOT;                 // 0..49151
        if (r < 24576) {                    // Kb pad rows
            const int bh = r / 512, rem = r % 512;
            const int n = kN + rem / 32, ch = rem % 32;
            Kb[((size_t)bh * kNP + n) * 32 + ch] = 0;
        } else {                            // Vb pad cols
            r -= 24576;
            const int bh = r / 512, rem = r % 512;
            const int ch = rem / 16, n = kN + rem % 16;
            Vb[((size_t)bh * 32 + ch) * kNP + n] = 0;
        }
    }
}

// ---------------------------------------------------------------------------
// K1: FUSED depthwise 3x3 conv + BN + 1x1 projection.
// Block = (32-position tile, branch, batch), 384 threads (6 waves).
// Phase A: dw+BN for 32 consecutive n x 192 ch -> LDS bf16 [32][200] (pad
//          stride 200 -> 2-way-free ds_read banks). Thread = fixed channel.
// Phase B: wave w projects o in [32w,32w+32) x 32 n via MFMA from LDS.
// Outputs: Q,K bf16 (b,h,n[kNP],ch), Q pre-scaled; V bf16 (b,h,ch,n[kNP]).
// ---------------------------------------------------------------------------
__global__ __launch_bounds__(384) void dwproj_kernel(
    const float* __restrict__ x,
    const float* __restrict__ wq, const float* __restrict__ gq,
    const float* __restrict__ bq, const float* __restrict__ mq,
    const float* __restrict__ vq,
    const float* __restrict__ wk, const float* __restrict__ gk,
    const float* __restrict__ bk, const float* __restrict__ mk,
    const float* __restrict__ vk,
    const float* __restrict__ wv, const float* __restrict__ gv,
    const float* __restrict__ bv, const float* __restrict__ mv,
    const float* __restrict__ vv,
    const unsigned short* __restrict__ Wq, const unsigned short* __restrict__ Wk,
    const unsigned short* __restrict__ Wv,
    const float* __restrict__ pqb, const float* __restrict__ pkb,
    const float* __restrict__ pvb,
    unsigned short* __restrict__ Qb, unsigned short* __restrict__ Kb,
    unsigned short* __restrict__ Vb)
{
    const int br = blockIdx.y;
    const int b  = blockIdx.z;
    const int n0 = blockIdx.x * 32;
    const int nvalid = min(32, kN - n0);
    const int t = threadIdx.x;

    __shared__ unsigned short Xs[32][200];

    // zero tail rows (only last tile, nvalid=16)
    if (nvalid < 32) {
        for (int idx = t; idx < (32 - nvalid) * 200; idx += 384)
            Xs[nvalid + idx / 200][idx % 200] = 0;
    }

    // ---- Phase A: depthwise conv + BN into LDS
    {
        const int c  = t % 192;
        const int nh = t / 192;   // 0 or 1 -> 16 positions each
        const float* dw = (br == 0) ? wq : (br == 1) ? wk : wv;
        const float* g_ = (br == 0) ? gq : (br == 1) ? gk : gv;
        const float* b_ = (br == 0) ? bq : (br == 1) ? bk : bv;
        const float* m_ = (br == 0) ? mq : (br == 1) ? mk : mv;
        const float* v_ = (br == 0) ? vq : (br == 1) ? vk : vv;
        float ww[9];
#pragma unroll
        for (int i = 0; i < 9; ++i) ww[i] = dw[c * 9 + i];
        const float inv = g_[c] * rsqrtf(v_[c] + kEPS);
        const float add = b_[c] - m_[c] * inv;
        const float* xb = x + (size_t)b * kN * kC + c;
        const int nlend = min(nh * 16 + 16, nvalid);
        for (int nl = nh * 16; nl < nlend; ++nl) {
            const int n = n0 + nl;
            const int i = n / kW, j = n % kW;
            float a = 0.f;
#pragma unroll
            for (int di = -1; di <= 1; ++di) {
                const int ii = i + di;
                if (ii < 0 || ii >= kH) continue;
#pragma unroll
                for (int dj = -1; dj <= 1; ++dj) {
                    const int jj = j + dj;
                    if (jj < 0 || jj >= kW) continue;
                    a += xb[(size_t)(ii * kW + jj) * kC] * ww[(di + 1) * 3 + dj + 1];
                }
            }
            Xs[nl][c] = f2bf(a * inv + add);
        }
    }
    __syncthreads();

    // ---- Phase B: projection MFMA
    const int w = t >> 6, l = t & 63, q16 = l & 15, u = l >> 4;
    const int ob = w * 32;
    const unsigned short* W = (br == 0) ? Wq : (br == 1) ? Wk : Wv;
    const float* bias       = (br == 0) ? pqb : (br == 1) ? pkb : pvb;

    f32x4 a00 = {0,0,0,0}, a01 = {0,0,0,0}, a10 = {0,0,0,0}, a11 = {0,0,0,0};
#pragma unroll
    for (int kk = 0; kk < 6; ++kk) {
        const bf16x8 wa0 = *(const bf16x8*)(W + (size_t)(ob + q16) * kC + u * 8 + kk * 32);
        const bf16x8 wa1 = *(const bf16x8*)(W + (size_t)(ob + 16 + q16) * kC + u * 8 + kk * 32);
        const bf16x8 xb0 = *(const bf16x8*)&Xs[q16][u * 8 + kk * 32];
        const bf16x8 xb1 = *(const bf16x8*)&Xs[16 + q16][u * 8 + kk * 32];
        a00 = __builtin_amdgcn_mfma_f32_16x16x32_bf16(wa0, xb0, a00, 0, 0, 0);
        a01 = __builtin_amdgcn_mfma_f32_16x16x32_bf16(wa0, xb1, a01, 0, 0, 0);
        a10 = __builtin_amdgcn_mfma_f32_16x16x32_bf16(wa1, xb0, a10, 0, 0, 0);
        a11 = __builtin_amdgcn_mfma_f32_16x16x32_bf16(wa1, xb1, a11, 0, 0, 0);
    }

    const float sc = (br == 0) ? kSCALE : 1.0f;
#pragma unroll
    for (int ot = 0; ot < 2; ++ot) {
        const int obase = ob + ot * 16;
        const int hh = obase >> 5;
        const int chb = (obase & 31) + 4 * u;
        const f32x4 bi = *(const f32x4*)&bias[obase + 4 * u];
#pragma unroll
        for (int nt = 0; nt < 2; ++nt) {
            const f32x4 A = (ot == 0) ? (nt == 0 ? a00 : a01)
                                      : (nt == 0 ? a10 : a11);
            const int n = n0 + nt * 16 + q16;
            if (n >= kN) continue;
            if (br < 2) {
                ushort4 p;
                p.x = f2bf((A[0] + bi[0]) * sc);
                p.y = f2bf((A[1] + bi[1]) * sc);
                p.z = f2bf((A[2] + bi[2]) * sc);
                p.w = f2bf((A[3] + bi[3]) * sc);
                unsigned short* dst = ((br == 0) ? Qb : Kb) +
                    ((size_t)(b * kHEADS + hh) * kNP + n) * 32 + chb;
                *(ushort4*)dst = p;
            } else {
                unsigned short* dst = Vb +
                    ((size_t)(b * kHEADS + hh) * 32 + chb) * kNP + n;
                dst[0 * kNP] = f2bf(A[0] + bi[0]);
                dst[1 * kNP] = f2bf(A[1] + bi[1]);
                dst[2 * kNP] = f2bf(A[2] + bi[2]);
                dst[3 * kNP] = f2bf(A[3] + bi[3]);
            }
        }
    }
}

// ---------------------------------------------------------------------------
// K2: attention. ONE WAVE per (b, head, 16-query tile): no LDS, no barriers.
// Swapped QK^T (d = mfma(K,Q)), online softmax with DEFER-MAX (THR=8):
// rescale only when tile max exceeds running max by >8 (never, for this
// data's tiny score scale) -> per-tile chain is max-tree + 2 shfl_xor +
// ballot + 8 exp + 4 cvt_pk. AO written bf16 (b, n[kXP], h*32+c).
// ---------------------------------------------------------------------------
__global__ __launch_bounds__(256) void attn_kernel(
    const unsigned short* __restrict__ Qbf, const unsigned short* __restrict__ Kbf,
    const unsigned short* __restrict__ Vbf, unsigned short* __restrict__ AO)
{
    const int wid = blockIdx.x * 4 + (threadIdx.x >> 6);
    const int l = threadIdx.x & 63;
    const int qt = wid % 49;
    const int h  = (wid / 49) % kHEADS;
    const int b  = wid / (49 * kHEADS);
    const int i0 = qt * 16;
    const int q16 = l & 15;
    const int u = l >> 4;

    const unsigned short* Qp = Qbf + ((size_t)(b * kHEADS + h) * kNP + i0) * 32;
    const unsigned short* Kp = Kbf + (size_t)(b * kHEADS + h) * kNP * 32;
    const unsigned short* Vr0 = Vbf + ((size_t)(b * kHEADS + h) * 32 + q16) * kNP;
    const unsigned short* Vr1 = Vr0 + (size_t)16 * kNP;

    const bf16x8 qa = *(const bf16x8*)(Qp + q16 * 32 + u * 8);

    f32x4 oa0 = {0.f, 0.f, 0.f, 0.f};
    f32x4 oa1 = {0.f, 0.f, 0.f, 0.f};
    float m = -1e30f, lsum = 0.f;

    for (int tile = 0; tile < 25; ++tile) {
        const int t0 = tile * 32;
        const bf16x8 ka0 = *(const bf16x8*)(Kp + (size_t)(t0 + q16) * 32 + u * 8);
        const bf16x8 ka1 = *(const bf16x8*)(Kp + (size_t)(t0 + 16 + q16) * 32 + u * 8);
        f32x4 d0 = {0.f, 0.f, 0.f, 0.f};
        f32x4 d1 = {0.f, 0.f, 0.f, 0.f};
        d0 = __builtin_amdgcn_mfma_f32_16x16x32_bf16(ka0, qa, d0, 0, 0, 0);
        d1 = __builtin_amdgcn_mfma_f32_16x16x32_bf16(ka1, qa, d1, 0, 0, 0);
        if (t0 + 16 >= kN) {  // last tile: keys t0+16.. are padding -> mask
            d1[0] = -1e30f; d1[1] = -1e30f; d1[2] = -1e30f; d1[3] = -1e30f;
        }
        // tile max for this query (reduce over the 4 u-lanes of query q16)
        float tm = fmaxf(fmaxf(fmaxf(d0[0], d0[1]), fmaxf(d0[2], d0[3])),
                         fmaxf(fmaxf(d1[0], d1[1]), fmaxf(d1[2], d1[3])));
        tm = fmaxf(tm, __shfl_xor(tm, 16));
        tm = fmaxf(tm, __shfl_xor(tm, 32));
        // defer-max: only rescale when the bound would be violated
        if (!__all(tm <= m + 8.0f)) {
            const float newm = fmaxf(m, tm);
            const float alpha = __expf(m - newm);
            m = newm;
            lsum *= alpha;
            const float al0 = __shfl(alpha, u * 4 + 0);
            const float al1 = __shfl(alpha, u * 4 + 1);
            const float al2 = __shfl(alpha, u * 4 + 2);
            const float al3 = __shfl(alpha, u * 4 + 3);
            oa0[0] *= al0; oa0[1] *= al1; oa0[2] *= al2; oa0[3] *= al3;
            oa1[0] *= al0; oa1[1] *= al1; oa1[2] *= al2; oa1[3] *= al3;
        }
        const float e0 = __expf(d0[0] - m), e1 = __expf(d0[1] - m);
        const float e2 = __expf(d0[2] - m), e3 = __expf(d0[3] - m);
        const float e4 = __expf(d1[0] - m), e5 = __expf(d1[1] - m);
        const float e6 = __expf(d1[2] - m), e7 = __expf(d1[3] - m);
        lsum += (((e0 + e1) + (e2 + e3)) + ((e4 + e5) + (e6 + e7)));
        // pack P to bf16 (lane-natural key order) via v_cvt_pk_bf16_f32
        union { unsigned int w[4]; bf16x8 v; } pa;
        asm("v_cvt_pk_bf16_f32 %0, %1, %2" : "=v"(pa.w[0]) : "v"(e0), "v"(e1));
        asm("v_cvt_pk_bf16_f32 %0, %1, %2" : "=v"(pa.w[1]) : "v"(e2), "v"(e3));
        asm("v_cvt_pk_bf16_f32 %0, %1, %2" : "=v"(pa.w[2]) : "v"(e4), "v"(e5));
        asm("v_cvt_pk_bf16_f32 %0, %1, %2" : "=v"(pa.w[3]) : "v"(e6), "v"(e7));
        // V B-fragments in the matching key order
        union { ushort4 hlf[2]; bf16x8 v; } v0, v1;
        v0.hlf[0] = *(const ushort4*)(Vr0 + t0 + 4 * u);
        v0.hlf[1] = *(const ushort4*)(Vr0 + t0 + 16 + 4 * u);
        v1.hlf[0] = *(const ushort4*)(Vr1 + t0 + 4 * u);
        v1.hlf[1] = *(const ushort4*)(Vr1 + t0 + 16 + 4 * u);
        oa0 = __builtin_amdgcn_mfma_f32_16x16x32_bf16(pa.v, v0.v, oa0, 0, 0, 0);
        oa1 = __builtin_amdgcn_mfma_f32_16x16x32_bf16(pa.v, v1.v, oa1, 0, 0, 0);
    }
    // full row sums and reciprocal
    lsum += __shfl_xor(lsum, 16);
    lsum += __shfl_xor(lsum, 32);
    const float rinv = 1.0f / lsum;
    const float r0 = __shfl(rinv, u * 4 + 0);
    const float r1 = __shfl(rinv, u * 4 + 1);
    const float r2 = __shfl(rinv, u * 4 + 2);
    const float r3 = __shfl(rinv, u * 4 + 3);
    // write AO[b][i0+4u+r][h*32 + {q16, 16+q16}]
    unsigned short* aw = AO + ((size_t)b * kXP + i0 + 4 * u) * kC + h * 32 + q16;
    aw[0 * kC + 0]  = f2bf(oa0[0] * r0);
    aw[1 * kC + 0]  = f2bf(oa0[1] * r1);
    aw[2 * kC + 0]  = f2bf(oa0[2] * r2);
    aw[3 * kC + 0]  = f2bf(oa0[3] * r3);
    aw[0 * kC + 16] = f2bf(oa1[0] * r0);
    aw[1 * kC + 16] = f2bf(oa1[1] * r1);
    aw[2 * kC + 16] = f2bf(oa1[2] * r2);
    aw[3 * kC + 16] = f2bf(oa1[3] * r3);
}

// ---------------------------------------------------------------------------
// K3: output projection. Y[o][n] = sum_u Wo'[o][u] AO[n][u] + pob[o],
// broadcast to g=0..3. Block 64o x 64n, wave = one 16-o tile x 64 n.
// ---------------------------------------------------------------------------
__global__ __launch_bounds__(256) void outproj_kernel(
    const unsigned short* __restrict__ AO, const unsigned short* __restrict__ Wo,
    const float* __restrict__ pob, float* __restrict__ Y)
{
    const int b = blockIdx.z;
    const int n0 = blockIdx.x * 64, o0 = blockIdx.y * 64;
    const int t = threadIdx.x, l = t & 63, w = t >> 6;
    const int q16 = l & 15, u = l >> 4;
    const int ob = o0 + w * 16;

    f32x4 c0 = {0,0,0,0}, c1 = {0,0,0,0}, c2 = {0,0,0,0}, c3 = {0,0,0,0};
    const unsigned short* Wr = Wo + (size_t)(ob + q16) * kC + u * 8;
    const unsigned short* Ar = AO + ((size_t)b * kXP + n0 + q16) * kC + u * 8;
#pragma unroll
    for (int kk = 0; kk < 6; ++kk) {
        const bf16x8 a = *(const bf16x8*)(Wr + kk * 32);
        const bf16x8 x0 = *(const bf16x8*)(Ar + (size_t)0 * 16 * kC + kk * 32);
        const bf16x8 x1 = *(const bf16x8*)(Ar + (size_t)1 * 16 * kC + kk * 32);
        const bf16x8 x2 = *(const bf16x8*)(Ar + (size_t)2 * 16 * kC + kk * 32);
        const bf16x8 x3 = *(const bf16x8*)(Ar + (size_t)3 * 16 * kC + kk * 32);
        c0 = __builtin_amdgcn_mfma_f32_16x16x32_bf16(a, x0, c0, 0, 0, 0);
        c1 = __builtin_amdgcn_mfma_f32_16x16x32_bf16(a, x1, c1, 0, 0, 0);
        c2 = __builtin_amdgcn_mfma_f32_16x16x32_bf16(a, x2, c2, 0, 0, 0);
        c3 = __builtin_amdgcn_mfma_f32_16x16x32_bf16(a, x3, c3, 0, 0, 0);
    }
    const float bi0 = pob[ob + 4 * u + 0];
    const float bi1 = pob[ob + 4 * u + 1];
    const float bi2 = pob[ob + 4 * u + 2];
    const float bi3 = pob[ob + 4 * u + 3];
#pragma unroll
    for (int nt = 0; nt < 4; ++nt) {
        const f32x4 A = (nt == 0) ? c0 : (nt == 1) ? c1 : (nt == 2) ? c2 : c3;
        const int n = n0 + nt * 16 + q16;
        if (n >= kN) continue;
#pragma unroll
        for (int r = 0; r < 4; ++r) {
            const int o = ob + 4 * u + r;
            const float val = A[r] + ((r == 0) ? bi0 : (r == 1) ? bi1
                                      : (r == 2) ? bi2 : bi3);
            float* yp = Y + (((size_t)b * kC + o) * kG) * kN + n;
            yp[0 * kN] = val;
            yp[1 * kN] = val;
            yp[2 * kN] = val;
            yp[3 * kN] = val;
        }
    }
}

extern "C" void kernel_launch(void* const* d_in, const int* in_sizes, int n_in,
                              void* d_out, int out_size, void* d_ws, size_t ws_size,
                              hipStream_t stream) {
    const float* x     = (const float*)d_in[0];
    // d_in[1]=h, d_in[2]=w (always 28; ignored)
    const float* dwq_w = (const float*)d_in[3];
    const float* bnq_g = (const float*)d_in[4];
    const float* bnq_b = (const float*)d_in[5];
    const float* bnq_m = (const float*)d_in[6];
    const float* bnq_v = (const float*)d_in[7];
    const float* pq_w  = (const float*)d_in[8];
    const float* pq_b  = (const float*)d_in[9];
    const float* dwk_w = (const float*)d_in[10];
    const float* bnk_g = (const float*)d_in[11];
    const float* bnk_b = (const float*)d_in[12];
    const float* bnk_m = (const float*)d_in[13];
    const float* bnk_v = (const float*)d_in[14];
    const float* pk_w  = (const float*)d_in[15];
    const float* pk_b  = (const float*)d_in[16];
    const float* dwv_w = (const float*)d_in[17];
    const float* bnv_g = (const float*)d_in[18];
    const float* bnv_b = (const float*)d_in[19];
    const float* bnv_m = (const float*)d_in[20];
    const float* bnv_v = (const float*)d_in[21];
    const float* pv_w  = (const float*)d_in[22];
    const float* pv_b  = (const float*)d_in[23];
    const float* po_w  = (const float*)d_in[24];
    const float* po_b  = (const float*)d_in[25];

    unsigned short* ws = (unsigned short*)d_ws;
    const size_t QSZ = (size_t)kB * kHEADS * kNP * 32;  // 1,228,800
    const size_t ASZ = (size_t)kB * kXP * kC;           // 1,277,952
    unsigned short* Qb = ws;
    unsigned short* Kb = Qb + QSZ;
    unsigned short* Vb = Kb + QSZ;
    unsigned short* AO = Vb + QSZ;
    unsigned short* Wq = AO + ASZ;
    unsigned short* Wk = Wq + kC * kC;
    unsigned short* Wv = Wk + kC * kC;
    unsigned short* Wo = Wv + kC * kC;

    prep_kernel<<<dim3(768), dim3(256), 0, stream>>>(
        pq_w, pk_w, pv_w, po_w, Wq, Wk, Wv, Wo, Kb, Vb);

    dwproj_kernel<<<dim3(25, 3, kB), dim3(384), 0, stream>>>(
        x,
        dwq_w, bnq_g, bnq_b, bnq_m, bnq_v,
        dwk_w, bnk_g, bnk_b, bnk_m, bnk_v,
        dwv_w, bnv_g, bnv_b, bnv_m, bnv_v,
        Wq, Wk, Wv, pq_b, pk_b, pv_b, Qb, Kb, Vb);

    attn_kernel<<<dim3(kB * kHEADS * 49 / 4), dim3(256), 0, stream>>>(
        Qb, Kb, Vb, AO);

    outproj_kernel<<<dim3(13, 3, kB), dim3(256), 0, stream>>>(
        AO, Wo, po_b, (float*)d_out);
}

// Round 5
// 79.148 us; speedup vs baseline: 1.2247x; 1.2247x over previous
//
#include <hip/hip_runtime.h>
#include <math.h>

// Problem constants (ConvAttention: B=8, C=192, H=W=28, heads=6, ch=32, G=4)
namespace {
constexpr int kB = 8;
constexpr int kC = 192;
constexpr int kH = 28;
constexpr int kW = 28;
constexpr int kN = 784;          // kH * kW
constexpr int kHEADS = 6;
constexpr int kG = 4;
constexpr float kEPS = 1e-5f;
constexpr float kSCALE = 0.07216878364870322f;  // 192^-0.5
constexpr int kNP = 800;         // padded key rows (25 tiles of 32)
constexpr int kXP = 832;         // padded n rows for X / AO (13 tiles of 64)

// dwprep block-role ranges
constexpr int kDWB = kB * 196;           // 1568 dw-conv blocks (4 pos each)
constexpr int kWCV = 192;                // weight-convert blocks
constexpr int kKVP = 32;                 // K/V pad-zero blocks
constexpr int kXAP = 192;                // X/AO pad-zero blocks
}

typedef __attribute__((ext_vector_type(8))) short bf16x8;
typedef __attribute__((ext_vector_type(4))) float f32x4;

// f32 -> bf16 bits, round-to-nearest-even
static __device__ __forceinline__ unsigned short f2bf(float f) {
    union { float f; unsigned int u; } v; v.f = f;
    unsigned int r = v.u + 0x7fffu + ((v.u >> 16) & 1u);
    return (unsigned short)(r >> 16);
}

// ---------------------------------------------------------------------------
// K1: depthwise 3x3 conv + BN (all 3 branches per x-load) + folded prep:
//   blocks [0,1568):   dw+BN, 4 positions x 192 ch -> Xq/Xk/Xv bf16 (b,n,c)
//   blocks [1568,1760): W f32->bf16 (Wo with (ch,heads)->(h*32+c) col perm)
//   blocks [1760,1792): zero K/V pad key rows [784,800)
//   blocks [1792,1984): zero Xq/Xk/Xv/AO pad rows [784,832)
// ---------------------------------------------------------------------------
__global__ __launch_bounds__(192) void dwprep_kernel(
    const float* __restrict__ x,
    const float* __restrict__ wq, const float* __restrict__ gq,
    const float* __restrict__ bq, const float* __restrict__ mq,
    const float* __restrict__ vq,
    const float* __restrict__ wk, const float* __restrict__ gk,
    const float* __restrict__ bk, const float* __restrict__ mk,
    const float* __restrict__ vk,
    const float* __restrict__ wv, const float* __restrict__ gv,
    const float* __restrict__ bv, const float* __restrict__ mv,
    const float* __restrict__ vv,
    const float* __restrict__ pqw, const float* __restrict__ pkw,
    const float* __restrict__ pvw, const float* __restrict__ pow_,
    unsigned short* __restrict__ xq, unsigned short* __restrict__ xk,
    unsigned short* __restrict__ xv,
    unsigned short* __restrict__ Wq, unsigned short* __restrict__ Wk,
    unsigned short* __restrict__ Wv, unsigned short* __restrict__ Wo,
    unsigned short* __restrict__ Kb, unsigned short* __restrict__ Vb)
{
    const int bx = blockIdx.x;
    const int t = threadIdx.x;

    if (bx < kDWB) {
        // ---- depthwise conv + BN, all 3 branches
        const int c = t;
        const int b = bx / 196;
        const int p0 = (bx % 196) * 4;

        float wwq[9], wwk[9], wwv[9];
#pragma unroll
        for (int i = 0; i < 9; ++i) {
            wwq[i] = wq[c * 9 + i];
            wwk[i] = wk[c * 9 + i];
            wwv[i] = wv[c * 9 + i];
        }
        const float invq = gq[c] * rsqrtf(vq[c] + kEPS);
        const float addq = bq[c] - mq[c] * invq;
        const float invk = gk[c] * rsqrtf(vk[c] + kEPS);
        const float addk = bk[c] - mk[c] * invk;
        const float invv = gv[c] * rsqrtf(vv[c] + kEPS);
        const float addv = bv[c] - mv[c] * invv;

        const float* xb = x + (size_t)b * kN * kC + c;
#pragma unroll
        for (int p = 0; p < 4; ++p) {
            const int n = p0 + p;
            const int i = n / kW;
            const int j = n % kW;
            float aq = 0.f, ak = 0.f, av = 0.f;
#pragma unroll
            for (int di = -1; di <= 1; ++di) {
                const int ii = i + di;
                if (ii < 0 || ii >= kH) continue;
#pragma unroll
                for (int dj = -1; dj <= 1; ++dj) {
                    const int jj = j + dj;
                    if (jj < 0 || jj >= kW) continue;
                    const float xvl = xb[(size_t)(ii * kW + jj) * kC];
                    const int tap = (di + 1) * 3 + (dj + 1);
                    aq += xvl * wwq[tap];
                    ak += xvl * wwk[tap];
                    av += xvl * wwv[tap];
                }
            }
            const size_t o = ((size_t)b * kXP + n) * kC + c;
            xq[o] = f2bf(aq * invq + addq);
            xk[o] = f2bf(ak * invk + addk);
            xv[o] = f2bf(av * invv + addv);
        }
    } else if (bx < kDWB + kWCV) {
        // ---- weight conversion, 4 elements per thread
        const int qidx = (bx - kDWB) * 192 + t;      // 0..36863
        const int e0 = qidx * 4;
        const int mat = e0 / (kC * kC);
        const int r = e0 % (kC * kC);
        if (mat < 3) {
            const float* src = (mat == 0) ? pqw : (mat == 1) ? pkw : pvw;
            unsigned short* dst = (mat == 0) ? Wq : (mat == 1) ? Wk : Wv;
            const f32x4 v = *(const f32x4*)&src[r];
            ushort4 p;
            p.x = f2bf(v[0]); p.y = f2bf(v[1]); p.z = f2bf(v[2]); p.w = f2bf(v[3]);
            *(ushort4*)&dst[r] = p;
        } else {
            const int o = r / kC, c0 = r % kC;
            ushort4 p;
            unsigned short* pp = &p.x;
#pragma unroll
            for (int e = 0; e < 4; ++e) {
                const int c = c0 + e;
                pp[e] = f2bf(pow_[o * kC + (c & 31) * kHEADS + (c >> 5)]);
            }
            *(ushort4*)&Wo[o * kC + c0] = p;
        }
    } else if (bx < kDWB + kWCV + kKVP) {
        // ---- K/V pad zero (8 shorts per thread)
        const int idx8 = (bx - kDWB - kWCV) * 192 + t;   // 0..6143
        const ushort4 z = {0, 0, 0, 0};
        if (idx8 < 3072) {       // K pads: 48 bh x 64 chunks
            const int bh = idx8 / 64, k = idx8 % 64;
            unsigned short* p = Kb + (size_t)bh * kNP * 32 + kN * 32 + k * 8;
            *(ushort4*)p = z; *(ushort4*)(p + 4) = z;
        } else {                 // V pads: 48 bh x 32 ch x 2 chunks
            const int c2 = idx8 - 3072;
            const int bh = c2 / 64, rem = c2 % 64;
            const int ch = rem >> 1, half = rem & 1;
            unsigned short* p = Vb + ((size_t)bh * 32 + ch) * kNP + kN + half * 8;
            *(ushort4*)p = z; *(ushort4*)(p + 4) = z;
        }
    } else {
        // ---- X/AO pad zero: 4 arrays (Xq,Xk,Xv,AO contiguous) x 9216 chunks
        const int c = (bx - kDWB - kWCV - kKVP) * 192 + t;  // 0..36863
        const int arr = c / 9216;
        const int r = c % 9216;
        const int b = r / 1152, rem = r % 1152;
        const int row = kN + rem / 24;
        const int col8 = (rem % 24) * 8;
        const size_t XSZ = (size_t)kB * kXP * kC;
        unsigned short* p = xq + (size_t)arr * XSZ + ((size_t)b * kXP + row) * kC + col8;
        const ushort4 z = {0, 0, 0, 0};
        *(ushort4*)p = z; *(ushort4*)(p + 4) = z;
    }
}

// ---------------------------------------------------------------------------
// K2: 1x1 projections via MFMA, no LDS. Out[o,n] = sum_c W[o,c] X[n,c] + b[o].
// Block: 64o x 64n tile, 4 waves each 32x32 (2x2 MFMA tiles), 6 k-steps.
// Q,K -> bf16 (b,h, n[kNP], ch) with Q pre-scaled by kSCALE.
// V   -> bf16 (b,h, ch, n[kNP]).
// ---------------------------------------------------------------------------
__global__ __launch_bounds__(256) void proj_kernel(
    const unsigned short* __restrict__ Xq, const unsigned short* __restrict__ Xk,
    const unsigned short* __restrict__ Xv,
    const unsigned short* __restrict__ Wq, const unsigned short* __restrict__ Wk,
    const unsigned short* __restrict__ Wv,
    const float* __restrict__ bq, const float* __restrict__ bk,
    const float* __restrict__ bv,
    unsigned short* __restrict__ Qb, unsigned short* __restrict__ Kb,
    unsigned short* __restrict__ Vb)
{
    const int br = blockIdx.z % 3;
    const int b  = blockIdx.z / 3;
    const unsigned short* X = (br == 0) ? Xq : (br == 1) ? Xk : Xv;
    const unsigned short* W = (br == 0) ? Wq : (br == 1) ? Wk : Wv;
    const float* bias       = (br == 0) ? bq : (br == 1) ? bk : bv;

    const int n0 = blockIdx.x * 64, o0 = blockIdx.y * 64;
    const int t = threadIdx.x, l = t & 63, w = t >> 6;
    const int q16 = l & 15, u = l >> 4;
    const int ob = o0 + (w >> 1) * 32;
    const int nb = n0 + (w & 1) * 32;

    f32x4 a00 = {0,0,0,0}, a01 = {0,0,0,0}, a10 = {0,0,0,0}, a11 = {0,0,0,0};
    const unsigned short* Wr0 = W + (size_t)(ob + q16) * kC + u * 8;
    const unsigned short* Wr1 = W + (size_t)(ob + 16 + q16) * kC + u * 8;
    const unsigned short* Xr0 = X + ((size_t)b * kXP + nb + q16) * kC + u * 8;
    const unsigned short* Xr1 = X + ((size_t)b * kXP + nb + 16 + q16) * kC + u * 8;
#pragma unroll
    for (int kk = 0; kk < 6; ++kk) {
        const bf16x8 wa0 = *(const bf16x8*)(Wr0 + kk * 32);
        const bf16x8 wa1 = *(const bf16x8*)(Wr1 + kk * 32);
        const bf16x8 xa0 = *(const bf16x8*)(Xr0 + kk * 32);
        const bf16x8 xa1 = *(const bf16x8*)(Xr1 + kk * 32);
        a00 = __builtin_amdgcn_mfma_f32_16x16x32_bf16(wa0, xa0, a00, 0, 0, 0);
        a01 = __builtin_amdgcn_mfma_f32_16x16x32_bf16(wa0, xa1, a01, 0, 0, 0);
        a10 = __builtin_amdgcn_mfma_f32_16x16x32_bf16(wa1, xa0, a10, 0, 0, 0);
        a11 = __builtin_amdgcn_mfma_f32_16x16x32_bf16(wa1, xa1, a11, 0, 0, 0);
    }

    const float sc = (br == 0) ? kSCALE : 1.0f;
#pragma unroll
    for (int ot = 0; ot < 2; ++ot) {
        const int obase = ob + ot * 16;
        const int hh = obase >> 5;
        const int chb = (obase & 31) + 4 * u;
        const f32x4 bi = *(const f32x4*)&bias[obase + 4 * u];
#pragma unroll
        for (int nt = 0; nt < 2; ++nt) {
            const f32x4 A = (ot == 0) ? (nt == 0 ? a00 : a01)
                                      : (nt == 0 ? a10 : a11);
            const int n = nb + nt * 16 + q16;
            if (n >= kNP) continue;
            if (br < 2) {
                ushort4 p;
                p.x = f2bf((A[0] + bi[0]) * sc);
                p.y = f2bf((A[1] + bi[1]) * sc);
                p.z = f2bf((A[2] + bi[2]) * sc);
                p.w = f2bf((A[3] + bi[3]) * sc);
                unsigned short* dst = ((br == 0) ? Qb : Kb) +
                    ((size_t)(b * kHEADS + hh) * kNP + n) * 32 + chb;
                *(ushort4*)dst = p;
            } else {
                unsigned short* dst = Vb +
                    ((size_t)(b * kHEADS + hh) * 32 + chb) * kNP + n;
                dst[0 * kNP] = f2bf(A[0] + bi[0]);
                dst[1 * kNP] = f2bf(A[1] + bi[1]);
                dst[2 * kNP] = f2bf(A[2] + bi[2]);
                dst[3 * kNP] = f2bf(A[3] + bi[3]);
            }
        }
    }
}

// ---------------------------------------------------------------------------
// K3: attention. ONE WAVE per (b, head, 16-query tile): no LDS, no barriers.
// Swapped QK^T (d = mfma(K,Q)), online softmax with defer-max (THR=8),
// P packed bf16 via v_cvt_pk_bf16_f32, PV with matching-key-order V frags.
// AO written bf16 (b, n[kXP], h*32+c).
// ---------------------------------------------------------------------------
__global__ __launch_bounds__(256) void attn_kernel(
    const unsigned short* __restrict__ Qbf, const unsigned short* __restrict__ Kbf,
    const unsigned short* __restrict__ Vbf, unsigned short* __restrict__ AO)
{
    const int wid = blockIdx.x * 4 + (threadIdx.x >> 6);
    const int l = threadIdx.x & 63;
    const int qt = wid % 49;
    const int h  = (wid / 49) % kHEADS;
    const int b  = wid / (49 * kHEADS);
    const int i0 = qt * 16;
    const int q16 = l & 15;
    const int u = l >> 4;

    const unsigned short* Qp = Qbf + ((size_t)(b * kHEADS + h) * kNP + i0) * 32;
    const unsigned short* Kp = Kbf + (size_t)(b * kHEADS + h) * kNP * 32;
    const unsigned short* Vr0 = Vbf + ((size_t)(b * kHEADS + h) * 32 + q16) * kNP;
    const unsigned short* Vr1 = Vr0 + (size_t)16 * kNP;

    const bf16x8 qa = *(const bf16x8*)(Qp + q16 * 32 + u * 8);

    f32x4 oa0 = {0.f, 0.f, 0.f, 0.f};
    f32x4 oa1 = {0.f, 0.f, 0.f, 0.f};
    float m = -1e30f, lsum = 0.f;

    for (int tile = 0; tile < 25; ++tile) {
        const int t0 = tile * 32;
        const bf16x8 ka0 = *(const bf16x8*)(Kp + (size_t)(t0 + q16) * 32 + u * 8);
        const bf16x8 ka1 = *(const bf16x8*)(Kp + (size_t)(t0 + 16 + q16) * 32 + u * 8);
        f32x4 d0 = {0.f, 0.f, 0.f, 0.f};
        f32x4 d1 = {0.f, 0.f, 0.f, 0.f};
        d0 = __builtin_amdgcn_mfma_f32_16x16x32_bf16(ka0, qa, d0, 0, 0, 0);
        d1 = __builtin_amdgcn_mfma_f32_16x16x32_bf16(ka1, qa, d1, 0, 0, 0);
        if (t0 + 16 >= kN) {  // last tile: keys t0+16.. are padding -> mask
            d1[0] = -1e30f; d1[1] = -1e30f; d1[2] = -1e30f; d1[3] = -1e30f;
        }
        float tm = fmaxf(fmaxf(fmaxf(d0[0], d0[1]), fmaxf(d0[2], d0[3])),
                         fmaxf(fmaxf(d1[0], d1[1]), fmaxf(d1[2], d1[3])));
        tm = fmaxf(tm, __shfl_xor(tm, 16));
        tm = fmaxf(tm, __shfl_xor(tm, 32));
        if (!__all(tm <= m + 8.0f)) {
            const float newm = fmaxf(m, tm);
            const float alpha = __expf(m - newm);
            m = newm;
            lsum *= alpha;
            const float al0 = __shfl(alpha, u * 4 + 0);
            const float al1 = __shfl(alpha, u * 4 + 1);
            const float al2 = __shfl(alpha, u * 4 + 2);
            const float al3 = __shfl(alpha, u * 4 + 3);
            oa0[0] *= al0; oa0[1] *= al1; oa0[2] *= al2; oa0[3] *= al3;
            oa1[0] *= al0; oa1[1] *= al1; oa1[2] *= al2; oa1[3] *= al3;
        }
        const float e0 = __expf(d0[0] - m), e1 = __expf(d0[1] - m);
        const float e2 = __expf(d0[2] - m), e3 = __expf(d0[3] - m);
        const float e4 = __expf(d1[0] - m), e5 = __expf(d1[1] - m);
        const float e6 = __expf(d1[2] - m), e7 = __expf(d1[3] - m);
        lsum += (((e0 + e1) + (e2 + e3)) + ((e4 + e5) + (e6 + e7)));
        union { unsigned int w[4]; bf16x8 v; } pa;
        asm("v_cvt_pk_bf16_f32 %0, %1, %2" : "=v"(pa.w[0]) : "v"(e0), "v"(e1));
        asm("v_cvt_pk_bf16_f32 %0, %1, %2" : "=v"(pa.w[1]) : "v"(e2), "v"(e3));
        asm("v_cvt_pk_bf16_f32 %0, %1, %2" : "=v"(pa.w[2]) : "v"(e4), "v"(e5));
        asm("v_cvt_pk_bf16_f32 %0, %1, %2" : "=v"(pa.w[3]) : "v"(e6), "v"(e7));
        union { ushort4 hlf[2]; bf16x8 v; } v0, v1;
        v0.hlf[0] = *(const ushort4*)(Vr0 + t0 + 4 * u);
        v0.hlf[1] = *(const ushort4*)(Vr0 + t0 + 16 + 4 * u);
        v1.hlf[0] = *(const ushort4*)(Vr1 + t0 + 4 * u);
        v1.hlf[1] = *(const ushort4*)(Vr1 + t0 + 16 + 4 * u);
        oa0 = __builtin_amdgcn_mfma_f32_16x16x32_bf16(pa.v, v0.v, oa0, 0, 0, 0);
        oa1 = __builtin_amdgcn_mfma_f32_16x16x32_bf16(pa.v, v1.v, oa1, 0, 0, 0);
    }
    lsum += __shfl_xor(lsum, 16);
    lsum += __shfl_xor(lsum, 32);
    const float rinv = 1.0f / lsum;
    const float r0 = __shfl(rinv, u * 4 + 0);
    const float r1 = __shfl(rinv, u * 4 + 1);
    const float r2 = __shfl(rinv, u * 4 + 2);
    const float r3 = __shfl(rinv, u * 4 + 3);
    unsigned short* aw = AO + ((size_t)b * kXP + i0 + 4 * u) * kC + h * 32 + q16;
    aw[0 * kC + 0]  = f2bf(oa0[0] * r0);
    aw[1 * kC + 0]  = f2bf(oa0[1] * r1);
    aw[2 * kC + 0]  = f2bf(oa0[2] * r2);
    aw[3 * kC + 0]  = f2bf(oa0[3] * r3);
    aw[0 * kC + 16] = f2bf(oa1[0] * r0);
    aw[1 * kC + 16] = f2bf(oa1[1] * r1);
    aw[2 * kC + 16] = f2bf(oa1[2] * r2);
    aw[3 * kC + 16] = f2bf(oa1[3] * r3);
}

// ---------------------------------------------------------------------------
// K4: output projection. Y[o][g][n] = sum_u Wo'[o][u] AO[n][u] + pob[o].
// Block 64o x 64n, wave = one 16-o tile x 64 n. Epilogue restages the tile
// in LDS and emits float4 stores (g=4 broadcast of contiguous 16-B chunks).
// ---------------------------------------------------------------------------
__global__ __launch_bounds__(256) void outproj_kernel(
    const unsigned short* __restrict__ AO, const unsigned short* __restrict__ Wo,
    const float* __restrict__ pob, float* __restrict__ Y)
{
    __shared__ float outs[64][68];

    const int b = blockIdx.z;
    const int n0 = blockIdx.x * 64, o0 = blockIdx.y * 64;
    const int t = threadIdx.x, l = t & 63, w = t >> 6;
    const int q16 = l & 15, u = l >> 4;
    const int ob = o0 + w * 16;

    f32x4 c0 = {0,0,0,0}, c1 = {0,0,0,0}, c2 = {0,0,0,0}, c3 = {0,0,0,0};
    const unsigned short* Wr = Wo + (size_t)(ob + q16) * kC + u * 8;
    const unsigned short* Ar = AO + ((size_t)b * kXP + n0 + q16) * kC + u * 8;
#pragma unroll
    for (int kk = 0; kk < 6; ++kk) {
        const bf16x8 a = *(const bf16x8*)(Wr + kk * 32);
        const bf16x8 x0 = *(const bf16x8*)(Ar + (size_t)0 * 16 * kC + kk * 32);
        const bf16x8 x1 = *(const bf16x8*)(Ar + (size_t)1 * 16 * kC + kk * 32);
        const bf16x8 x2 = *(const bf16x8*)(Ar + (size_t)2 * 16 * kC + kk * 32);
        const bf16x8 x3 = *(const bf16x8*)(Ar + (size_t)3 * 16 * kC + kk * 32);
        c0 = __builtin_amdgcn_mfma_f32_16x16x32_bf16(a, x0, c0, 0, 0, 0);
        c1 = __builtin_amdgcn_mfma_f32_16x16x32_bf16(a, x1, c1, 0, 0, 0);
        c2 = __builtin_amdgcn_mfma_f32_16x16x32_bf16(a, x2, c2, 0, 0, 0);
        c3 = __builtin_amdgcn_mfma_f32_16x16x32_bf16(a, x3, c3, 0, 0, 0);
    }
    const f32x4 bi = *(const f32x4*)&pob[ob + 4 * u];
#pragma unroll
    for (int nt = 0; nt < 4; ++nt) {
        const f32x4 A = (nt == 0) ? c0 : (nt == 1) ? c1 : (nt == 2) ? c2 : c3;
#pragma unroll
        for (int r = 0; r < 4; ++r)
            outs[w * 16 + 4 * u + r][nt * 16 + q16] = A[r] + bi[r];
    }
    __syncthreads();

    // vectorized g-broadcast store: thread -> (o row, 16-n quarter)
    const int ol = t >> 2;
    const int nq = (t & 3) * 16;
    const int nbase = n0 + nq;
    if (nbase < kN) {
        f32x4 v0 = *(const f32x4*)&outs[ol][nq + 0];
        f32x4 v1 = *(const f32x4*)&outs[ol][nq + 4];
        f32x4 v2 = *(const f32x4*)&outs[ol][nq + 8];
        f32x4 v3 = *(const f32x4*)&outs[ol][nq + 12];
        const int o = o0 + ol;
        float* yp = Y + (((size_t)b * kC + o) * kG) * kN + nbase;
#pragma unroll
        for (int g = 0; g < kG; ++g) {
            *(f32x4*)&yp[g * kN + 0]  = v0;
            *(f32x4*)&yp[g * kN + 4]  = v1;
            *(f32x4*)&yp[g * kN + 8]  = v2;
            *(f32x4*)&yp[g * kN + 12] = v3;
        }
    }
}

extern "C" void kernel_launch(void* const* d_in, const int* in_sizes, int n_in,
                              void* d_out, int out_size, void* d_ws, size_t ws_size,
                              hipStream_t stream) {
    const float* x     = (const float*)d_in[0];
    // d_in[1]=h, d_in[2]=w (always 28; ignored)
    const float* dwq_w = (const float*)d_in[3];
    const float* bnq_g = (const float*)d_in[4];
    const float* bnq_b = (const float*)d_in[5];
    const float* bnq_m = (const float*)d_in[6];
    const float* bnq_v = (const float*)d_in[7];
    const float* pq_w  = (const float*)d_in[8];
    const float* pq_b  = (const float*)d_in[9];
    const float* dwk_w = (const float*)d_in[10];
    const float* bnk_g = (const float*)d_in[11];
    const float* bnk_b = (const float*)d_in[12];
    const float* bnk_m = (const float*)d_in[13];
    const float* bnk_v = (const float*)d_in[14];
    const float* pk_w  = (const float*)d_in[15];
    const float* pk_b  = (const float*)d_in[16];
    const float* dwv_w = (const float*)d_in[17];
    const float* bnv_g = (const float*)d_in[18];
    const float* bnv_b = (const float*)d_in[19];
    const float* bnv_m = (const float*)d_in[20];
    const float* bnv_v = (const float*)d_in[21];
    const float* pv_w  = (const float*)d_in[22];
    const float* pv_b  = (const float*)d_in[23];
    const float* po_w  = (const float*)d_in[24];
    const float* po_b  = (const float*)d_in[25];

    unsigned short* ws = (unsigned short*)d_ws;
    const size_t XSZ = (size_t)kB * kXP * kC;           // 1,277,952
    const size_t QSZ = (size_t)kB * kHEADS * kNP * 32;  // 1,228,800
    unsigned short* Xq = ws;                 // [Xq][Xk][Xv][AO] contiguous
    unsigned short* Xk = Xq + XSZ;
    unsigned short* Xv = Xk + XSZ;
    unsigned short* AO = Xv + XSZ;
    unsigned short* Qb = AO + XSZ;
    unsigned short* Kb = Qb + QSZ;
    unsigned short* Vb = Kb + QSZ;
    unsigned short* Wq = Vb + QSZ;
    unsigned short* Wk = Wq + kC * kC;
    unsigned short* Wv = Wk + kC * kC;
    unsigned short* Wo = Wv + kC * kC;

    dwprep_kernel<<<dim3(kDWB + kWCV + kKVP + kXAP), dim3(192), 0, stream>>>(
        x,
        dwq_w, bnq_g, bnq_b, bnq_m, bnq_v,
        dwk_w, bnk_g, bnk_b, bnk_m, bnk_v,
        dwv_w, bnv_g, bnv_b, bnv_m, bnv_v,
        pq_w, pk_w, pv_w, po_w,
        Xq, Xk, Xv, Wq, Wk, Wv, Wo, Kb, Vb);

    proj_kernel<<<dim3(13, 3, kB * 3), dim3(256), 0, stream>>>(
        Xq, Xk, Xv, Wq, Wk, Wv, pq_b, pk_b, pv_b, Qb, Kb, Vb);

    attn_kernel<<<dim3(kB * kHEADS * 49 / 4), dim3(256), 0, stream>>>(
        Qb, Kb, Vb, AO);

    outproj_kernel<<<dim3(13, 3, kB), dim3(256), 0, stream>>>(
        AO, Wo, po_b, (float*)d_out);
}